// Round 1
// baseline (274.590 us; speedup 1.0000x reference)
//
#include <hip/hip_runtime.h>
#include <hip/hip_bf16.h>
#include <cstdint>
#include <cstddef>

#define BATCH 8
#define SEQ   4096
#define CDIM  384
#define HDIM  64

typedef __attribute__((ext_vector_type(8))) __bf16 bf16x8;
typedef __attribute__((ext_vector_type(4))) float  f32x4;
typedef __attribute__((ext_vector_type(4))) short  short4v;

static __device__ __forceinline__ short f2bf(float f) {
  union { float f; uint32_t u; } v; v.f = f;
  uint32_t r = v.u + 0x7fffu + ((v.u >> 16) & 1u);
  return (short)(r >> 16);
}

static __device__ __forceinline__ f32x4 mfma16(bf16x8 a, bf16x8 b, f32x4 c) {
  return __builtin_amdgcn_mfma_f32_16x16x32_bf16(a, b, c, 0, 0, 0);
}

static __device__ __forceinline__ f32x4 zero4() {
  f32x4 z = {0.f, 0.f, 0.f, 0.f};
  return z;
}

// ---------------------------------------------------------------------------
// Pack Wq|Wk|Wv (each [C][H] f32) into Wt [192][384] bf16, transposed so that
// row n (= output col), col c (= K dim) is contiguous along K.
// ---------------------------------------------------------------------------
__global__ __launch_bounds__(256) void wpack_kernel(
    const float* __restrict__ Wq, const float* __restrict__ Wk,
    const float* __restrict__ Wv, short* __restrict__ Wt) {
  int idx = blockIdx.x * 256 + threadIdx.x;  // 192*384 = 73728
  if (idx >= 192 * CDIM) return;
  int n = idx / CDIM;
  int c = idx - n * CDIM;
  int m = n >> 6, h = n & 63;
  const float* W = (m == 0) ? Wq : (m == 1) ? Wk : Wv;
  Wt[idx] = f2bf(W[c * HDIM + h]);
}

// ---------------------------------------------------------------------------
// QKV projection: x [32768][384] f32 -> q,k [b][t][64] bf16, v transposed
// vT [b][64][t] bf16.  One block = 64 tokens, 4 waves; wave w computes all 64
// rows x 48 cols (n-tiles w*3..w*3+2).
// ---------------------------------------------------------------------------
#define XPAD 392  // 384 + 8 pad (2-way LDS aliasing only — free)

__global__ __launch_bounds__(256) void qkv_kernel(
    const float* __restrict__ x, const short* __restrict__ Wt,
    short* __restrict__ qb, short* __restrict__ kb, short* __restrict__ vT) {
  __shared__ short xs[64 * XPAD];
  const int tid = threadIdx.x;
  const int tokbase = blockIdx.x * 64;

  // stage x tile -> bf16 LDS (float4 loads, 24 iter/thread)
  const float4* xg = (const float4*)(x + (size_t)tokbase * CDIM);
  for (int it = tid; it < 64 * (CDIM / 4); it += 256) {
    int r  = it / (CDIM / 4);
    int c4 = it - r * (CDIM / 4);
    float4 v = xg[it];
    short4v s;
    s[0] = f2bf(v.x); s[1] = f2bf(v.y); s[2] = f2bf(v.z); s[3] = f2bf(v.w);
    *(short4v*)&xs[r * XPAD + c4 * 4] = s;
  }
  __syncthreads();

  const int wave = tid >> 6;
  const int lane = tid & 63;
  const int l16  = lane & 15;
  const int lq   = lane >> 4;

  f32x4 acc[4][3];
  #pragma unroll
  for (int ai = 0; ai < 4; ++ai)
    #pragma unroll
    for (int j = 0; j < 3; ++j) acc[ai][j] = zero4();

  #pragma unroll 2
  for (int kk = 0; kk < CDIM / 32; ++kk) {
    const int k0 = kk * 32;
    bf16x8 a[4];
    #pragma unroll
    for (int ai = 0; ai < 4; ++ai)
      a[ai] = *(const bf16x8*)&xs[(ai * 16 + l16) * XPAD + k0 + lq * 8];
    bf16x8 bb[3];
    #pragma unroll
    for (int j = 0; j < 3; ++j) {
      const int nt = wave * 3 + j;
      bb[j] = *(const bf16x8*)&Wt[(size_t)(nt * 16 + l16) * CDIM + k0 + lq * 8];
    }
    #pragma unroll
    for (int ai = 0; ai < 4; ++ai)
      #pragma unroll
      for (int j = 0; j < 3; ++j)
        acc[ai][j] = mfma16(a[ai], bb[j], acc[ai][j]);
  }

  const int b     = tokbase >> 12;        // tokbase / 4096
  const int tloc0 = tokbase & (SEQ - 1);
  #pragma unroll
  for (int j = 0; j < 3; ++j) {
    const int col = (wave * 3 + j) * 16 + l16;
    const int mat = col >> 6;   // uniform per n-tile (16 | 64)
    const int h   = col & 63;
    #pragma unroll
    for (int ai = 0; ai < 4; ++ai) {
      const int row0 = ai * 16 + lq * 4;
      if (mat < 2) {
        short* dst = mat ? kb : qb;
        #pragma unroll
        for (int r = 0; r < 4; ++r)
          dst[(size_t)(tokbase + row0 + r) * HDIM + h] = f2bf(acc[ai][j][r]);
      } else {
        short4v s;
        #pragma unroll
        for (int r = 0; r < 4; ++r) s[r] = f2bf(acc[ai][j][r]);
        *(short4v*)&vT[(size_t)(b * HDIM + h) * SEQ + (tloc0 + row0)] = s;
      }
    }
  }
}

// ---------------------------------------------------------------------------
// Causal flash attention.  Block = 64 Q rows (4 waves x 16 rows), KVBLK = 64.
// Online softmax fully wave-parallel; P transposed through per-wave LDS.
// Q-tiles launched in reverse (heavy blocks first) for load balance.
// ---------------------------------------------------------------------------
#define PPAD 72  // 64 + 8 pad

__global__ __launch_bounds__(256) void attn_kernel(
    const short* __restrict__ qb, const short* __restrict__ kb,
    const short* __restrict__ vT, float* __restrict__ out) {
  __shared__ short plds[4 * 16 * PPAD];
  const int tid  = threadIdx.x;
  const int wave = tid >> 6;
  const int lane = tid & 63;
  const int l16  = lane & 15;
  const int lq   = lane >> 4;
  const int b    = blockIdx.y;
  const int qt   = gridDim.x - 1 - blockIdx.x;  // reversed: long KV first
  const int qs   = qt * 64;
  const int wrow0  = qs + wave * 16;
  const int myrow0 = wrow0 + lq * 4;

  // Q fragments (held for the whole block)
  bf16x8 qf[2];
  {
    const short* qrow = qb + (size_t)(b * SEQ + wrow0 + l16) * HDIM;
    qf[0] = *(const bf16x8*)&qrow[lq * 8];
    qf[1] = *(const bf16x8*)&qrow[32 + lq * 8];
  }

  f32x4 acc[4];
  #pragma unroll
  for (int j = 0; j < 4; ++j) acc[j] = zero4();
  float m[4], l[4];
  #pragma unroll
  for (int r = 0; r < 4; ++r) { m[r] = -1e30f; l[r] = 0.f; }

  short* myp = &plds[wave * 16 * PPAD];
  const int nkv = qt + 1;

  for (int it = 0; it < nkv; ++it) {
    const int s0 = it * 64;
    // ---- S = (Q K^T) * 0.125, causal-masked ----
    f32x4 sacc[4];
    #pragma unroll
    for (int n = 0; n < 4; ++n) sacc[n] = zero4();
    #pragma unroll
    for (int n = 0; n < 4; ++n) {
      const short* krow = kb + (size_t)(b * SEQ + s0 + n * 16 + l16) * HDIM;
      bf16x8 k0f = *(const bf16x8*)&krow[lq * 8];
      bf16x8 k1f = *(const bf16x8*)&krow[32 + lq * 8];
      sacc[n] = mfma16(qf[0], k0f, sacc[n]);
      sacc[n] = mfma16(qf[1], k1f, sacc[n]);
    }
    #pragma unroll
    for (int n = 0; n < 4; ++n)
      #pragma unroll
      for (int r = 0; r < 4; ++r) sacc[n][r] *= 0.125f;
    if (s0 + 63 > wrow0) {  // wave-uniform: only diagonal tiles mask
      #pragma unroll
      for (int n = 0; n < 4; ++n) {
        const int col = s0 + n * 16 + l16;
        #pragma unroll
        for (int r = 0; r < 4; ++r)
          if (col > myrow0 + r) sacc[n][r] = -1e30f;
      }
    }
    // ---- row max (4 rows/lane, 16-lane xor reduce) ----
    float pm[4];
    #pragma unroll
    for (int r = 0; r < 4; ++r)
      pm[r] = fmaxf(fmaxf(sacc[0][r], sacc[1][r]), fmaxf(sacc[2][r], sacc[3][r]));
    #pragma unroll
    for (int off = 1; off < 16; off <<= 1) {
      #pragma unroll
      for (int r = 0; r < 4; ++r)
        pm[r] = fmaxf(pm[r], __shfl_xor(pm[r], off, 64));
    }
    float scale[4];
    #pragma unroll
    for (int r = 0; r < 4; ++r) {
      const float mn = fmaxf(m[r], pm[r]);
      scale[r] = __expf(m[r] - mn);
      m[r] = mn;
    }
    // ---- P = exp(S - m): row sums + bf16 into LDS (transpose for PV A-frag)
    float rsum[4];
    #pragma unroll
    for (int r = 0; r < 4; ++r) {
      const int row = lq * 4 + r;
      float p0 = __expf(sacc[0][r] - m[r]);
      float p1 = __expf(sacc[1][r] - m[r]);
      float p2 = __expf(sacc[2][r] - m[r]);
      float p3 = __expf(sacc[3][r] - m[r]);
      rsum[r] = (p0 + p1) + (p2 + p3);
      myp[row * PPAD +      l16] = f2bf(p0);
      myp[row * PPAD + 16 + l16] = f2bf(p1);
      myp[row * PPAD + 32 + l16] = f2bf(p2);
      myp[row * PPAD + 48 + l16] = f2bf(p3);
    }
    #pragma unroll
    for (int off = 1; off < 16; off <<= 1) {
      #pragma unroll
      for (int r = 0; r < 4; ++r)
        rsum[r] += __shfl_xor(rsum[r], off, 64);
    }
    #pragma unroll
    for (int r = 0; r < 4; ++r) l[r] = l[r] * scale[r] + rsum[r];
    #pragma unroll
    for (int j = 0; j < 4; ++j)
      #pragma unroll
      for (int r = 0; r < 4; ++r) acc[j][r] *= scale[r];
    // ---- O += P V  (P A-frags from LDS, V B-frags from vT, contiguous) ----
    bf16x8 pf0 = *(const bf16x8*)&myp[l16 * PPAD +      lq * 8];
    bf16x8 pf1 = *(const bf16x8*)&myp[l16 * PPAD + 32 + lq * 8];
    #pragma unroll
    for (int j = 0; j < 4; ++j) {
      const short* vrow = vT + (size_t)(b * HDIM + j * 16 + l16) * SEQ + s0;
      bf16x8 v0f = *(const bf16x8*)&vrow[lq * 8];
      bf16x8 v1f = *(const bf16x8*)&vrow[32 + lq * 8];
      acc[j] = mfma16(pf0, v0f, acc[j]);
      acc[j] = mfma16(pf1, v1f, acc[j]);
    }
  }

  float inv[4];
  #pragma unroll
  for (int r = 0; r < 4; ++r) inv[r] = 1.0f / l[r];
  #pragma unroll
  for (int j = 0; j < 4; ++j)
    #pragma unroll
    for (int r = 0; r < 4; ++r)
      out[(size_t)(b * SEQ + myrow0 + r) * HDIM + j * 16 + l16] =
          acc[j][r] * inv[r];
}

// ---------------------------------------------------------------------------
extern "C" void kernel_launch(void* const* d_in, const int* in_sizes, int n_in,
                              void* d_out, int out_size, void* d_ws, size_t ws_size,
                              hipStream_t stream) {
  (void)in_sizes; (void)n_in; (void)out_size; (void)ws_size;
  const float* x  = (const float*)d_in[0];
  const float* Wq = (const float*)d_in[1];
  const float* Wk = (const float*)d_in[2];
  const float* Wv = (const float*)d_in[3];

  const size_t qkvb = (size_t)BATCH * SEQ * HDIM * sizeof(short);  // 4 MB each
  char* ws = (char*)d_ws;
  short* qb = (short*)(ws);
  short* kb = (short*)(ws + qkvb);
  short* vT = (short*)(ws + 2 * qkvb);
  short* Wt = (short*)(ws + 3 * qkvb);  // 147 KB; total ws use ~12.7 MB

  wpack_kernel<<<dim3((192 * CDIM + 255) / 256), dim3(256), 0, stream>>>(Wq, Wk, Wv, Wt);
  qkv_kernel<<<dim3(BATCH * SEQ / 64), dim3(256), 0, stream>>>(x, Wt, qb, kb, vT);
  attn_kernel<<<dim3(SEQ / 64, BATCH), dim3(256), 0, stream>>>(qb, kb, vT, (float*)d_out);
}

// Round 2
// 205.713 us; speedup vs baseline: 1.3348x; 1.3348x over previous
//
#include <hip/hip_runtime.h>
#include <hip/hip_bf16.h>
#include <cstdint>
#include <cstddef>

#define BATCH 8
#define SEQ   4096
#define CDIM  384
#define HDIM  64

typedef __attribute__((ext_vector_type(8))) __bf16 bf16x8;
typedef __attribute__((ext_vector_type(4))) float  f32x4;
typedef __attribute__((ext_vector_type(4))) short  short4v;

#if __has_builtin(__builtin_amdgcn_mfma_f32_16x16x16bf16_1k)
#define HAVE_MFMA161616 1
#else
#define HAVE_MFMA161616 0
#endif

static __device__ __forceinline__ short f2bf(float f) {
  union { float f; uint32_t u; } v; v.f = f;
  uint32_t r = v.u + 0x7fffu + ((v.u >> 16) & 1u);
  return (short)(r >> 16);
}

static __device__ __forceinline__ f32x4 mfma16(bf16x8 a, bf16x8 b, f32x4 c) {
  return __builtin_amdgcn_mfma_f32_16x16x32_bf16(a, b, c, 0, 0, 0);
}

static __device__ __forceinline__ f32x4 zero4() {
  f32x4 z = {0.f, 0.f, 0.f, 0.f};
  return z;
}

// ---------------------------------------------------------------------------
// Pack Wq|Wk|Wv into Wt [192][384] bf16 (transposed, K contiguous).
// Wq rows are prescaled by 0.125*log2(e) so attention softmax runs in base 2
// with no per-element scale multiply.
// ---------------------------------------------------------------------------
__global__ __launch_bounds__(256) void wpack_kernel(
    const float* __restrict__ Wq, const float* __restrict__ Wk,
    const float* __restrict__ Wv, short* __restrict__ Wt) {
  int idx = blockIdx.x * 256 + threadIdx.x;  // 192*384 = 73728
  if (idx >= 192 * CDIM) return;
  int n = idx / CDIM;
  int c = idx - n * CDIM;
  int m = n >> 6, h = n & 63;
  const float* W = (m == 0) ? Wq : (m == 1) ? Wk : Wv;
  float s = (m == 0) ? 0.18033688011112042f : 1.0f;  // 0.125 * log2(e)
  Wt[idx] = f2bf(W[c * HDIM + h] * s);
}

// ---------------------------------------------------------------------------
// QKV projection: x [32768][384] f32 -> q,k [b][t][64] bf16, v transposed
// vT [b][64][t] bf16.
// ---------------------------------------------------------------------------
#define XPAD 392

__global__ __launch_bounds__(256) void qkv_kernel(
    const float* __restrict__ x, const short* __restrict__ Wt,
    short* __restrict__ qb, short* __restrict__ kb, short* __restrict__ vT) {
  __shared__ short xs[64 * XPAD];
  const int tid = threadIdx.x;
  const int tokbase = blockIdx.x * 64;

  const float4* xg = (const float4*)(x + (size_t)tokbase * CDIM);
  for (int it = tid; it < 64 * (CDIM / 4); it += 256) {
    int r  = it / (CDIM / 4);
    int c4 = it - r * (CDIM / 4);
    float4 v = xg[it];
    short4v s;
    s[0] = f2bf(v.x); s[1] = f2bf(v.y); s[2] = f2bf(v.z); s[3] = f2bf(v.w);
    *(short4v*)&xs[r * XPAD + c4 * 4] = s;
  }
  __syncthreads();

  const int wave = tid >> 6;
  const int lane = tid & 63;
  const int l16  = lane & 15;
  const int lq   = lane >> 4;

  f32x4 acc[4][3];
  #pragma unroll
  for (int ai = 0; ai < 4; ++ai)
    #pragma unroll
    for (int j = 0; j < 3; ++j) acc[ai][j] = zero4();

  #pragma unroll 2
  for (int kk = 0; kk < CDIM / 32; ++kk) {
    const int k0 = kk * 32;
    bf16x8 a[4];
    #pragma unroll
    for (int ai = 0; ai < 4; ++ai)
      a[ai] = *(const bf16x8*)&xs[(ai * 16 + l16) * XPAD + k0 + lq * 8];
    bf16x8 bb[3];
    #pragma unroll
    for (int j = 0; j < 3; ++j) {
      const int nt = wave * 3 + j;
      bb[j] = *(const bf16x8*)&Wt[(size_t)(nt * 16 + l16) * CDIM + k0 + lq * 8];
    }
    #pragma unroll
    for (int ai = 0; ai < 4; ++ai)
      #pragma unroll
      for (int j = 0; j < 3; ++j)
        acc[ai][j] = mfma16(a[ai], bb[j], acc[ai][j]);
  }

  const int b     = tokbase >> 12;
  const int tloc0 = tokbase & (SEQ - 1);
  #pragma unroll
  for (int j = 0; j < 3; ++j) {
    const int col = (wave * 3 + j) * 16 + l16;
    const int mat = col >> 6;
    const int h   = col & 63;
    #pragma unroll
    for (int ai = 0; ai < 4; ++ai) {
      const int row0 = ai * 16 + lq * 4;
      if (mat < 2) {
        short* dst = mat ? kb : qb;
        #pragma unroll
        for (int r = 0; r < 4; ++r)
          dst[(size_t)(tokbase + row0 + r) * HDIM + h] = f2bf(acc[ai][j][r]);
      } else {
        short4v s;
        #pragma unroll
        for (int r = 0; r < 4; ++r) s[r] = f2bf(acc[ai][j][r]);
        *(short4v*)&vT[(size_t)(b * HDIM + h) * SEQ + (tloc0 + row0)] = s;
      }
    }
  }
}

// ---------------------------------------------------------------------------
// Causal flash attention, swapped-operand form (no LDS, no barriers).
// Block = 4 independent waves; wave w of block (b,i) handles q-tile
// {i, 127-i, 128+i, 255-i}[w] (16 rows) -> every block does ~130 KV iters.
// Per lane: q-column = l16 (4 lanes lq=0..3 partition s); softmax state m,l
// are per-lane scalars.  S^T via mfma(K,Q); PV via 16x16x16 mfma whose B-frag
// layout equals the S^T register layout (no cross-lane exchange).
// ---------------------------------------------------------------------------
__global__ __launch_bounds__(256) void attn_kernel(
    const short* __restrict__ qb, const short* __restrict__ kb,
    const short* __restrict__ vT, float* __restrict__ out) {
  const int tid  = threadIdx.x;
  const int wave = tid >> 6;
  const int lane = tid & 63;
  const int l16  = lane & 15;
  const int lq   = lane >> 4;
  const int bid  = blockIdx.x;
  const int b    = bid & 7;           // batch -> XCD pin (L2 locality)
  const int i    = bid >> 3;          // 0..63
  const int qt16 = (wave == 0) ? i : (wave == 1) ? 127 - i
                 : (wave == 2) ? 128 + i : 255 - i;
  const int q0   = qt16 << 4;
  const int nkv  = (qt16 >> 2) + 1;

  const size_t bT = (size_t)b * SEQ;

  // Q fragments (B-operand; prescaled by 0.125*log2e at wpack)
  bf16x8 qf0, qf1;
  {
    const short* qrow = qb + (bT + q0 + l16) * HDIM + lq * 8;
    qf0 = *(const bf16x8*)qrow;
    qf1 = *(const bf16x8*)(qrow + 32);
  }

  f32x4 oacc[4];
  #pragma unroll
  for (int j = 0; j < 4; ++j) oacc[j] = zero4();
  float m = -1e30f, l = 0.f;

  const short* kbase = kb + bT * HDIM + lq * 8;  // + s*64 (+32 for upper half)
  const short* vrow0 = vT + ((size_t)b * HDIM + l16) * SEQ;  // + j*16*SEQ + s

  // preload K(0)
  bf16x8 kc[4][2];
  #pragma unroll
  for (int n = 0; n < 4; ++n) {
    const short* kr = kbase + (size_t)(n * 16 + l16) * HDIM;
    kc[n][0] = *(const bf16x8*)kr;
    kc[n][1] = *(const bf16x8*)(kr + 32);
  }

  #pragma unroll 2
  for (int it = 0; it < nkv; ++it) {
    const int s0  = it * 64;
    const int s0n = (it + 1 < nkv) ? s0 + 64 : s0;

    // ---- issue V loads for this iter (consumed at the end) ----
#if HAVE_MFMA161616
    short4v vf[4][4];
    #pragma unroll
    for (int j = 0; j < 4; ++j)
      #pragma unroll
      for (int n = 0; n < 4; ++n)
        vf[j][n] = *(const short4v*)(vrow0 + (size_t)(j * 16) * SEQ +
                                     s0 + n * 16 + lq * 4);
#else
    bf16x8 vf[4][2];
    #pragma unroll
    for (int j = 0; j < 4; ++j)
      #pragma unroll
      for (int sh = 0; sh < 2; ++sh)
        vf[j][sh] = *(const bf16x8*)(vrow0 + (size_t)(j * 16) * SEQ +
                                     s0 + sh * 32 + lq * 8);
#endif
    // ---- prefetch K(it+1) ----
    bf16x8 kn[4][2];
    #pragma unroll
    for (int n = 0; n < 4; ++n) {
      const short* kr = kbase + (size_t)(s0n + n * 16 + l16) * HDIM;
      kn[n][0] = *(const bf16x8*)kr;
      kn[n][1] = *(const bf16x8*)(kr + 32);
    }

    // ---- S^T = mfma(K, Q): sacc[n][r] = S[q=l16][s=s0+n*16+lq*4+r] ----
    f32x4 sacc[4];
    #pragma unroll
    for (int n = 0; n < 4; ++n) {
      sacc[n] = mfma16(kc[n][0], qf0, zero4());
      sacc[n] = mfma16(kc[n][1], qf1, sacc[n]);
    }

    // ---- causal mask (diagonal tile only; wave-uniform branch) ----
    if (s0 + 63 > q0) {
      const int qg = q0 + l16;
      #pragma unroll
      for (int n = 0; n < 4; ++n) {
        const int sg = s0 + n * 16 + lq * 4;
        #pragma unroll
        for (int r = 0; r < 4; ++r)
          if (sg + r > qg) sacc[n][r] = -1e30f;
      }
    }

    // ---- per-q max: in-register tree + 2 shfl_xor (lanes lq=0..3) ----
    float pm;
    {
      float t0 = fmaxf(fmaxf(sacc[0][0], sacc[0][1]), fmaxf(sacc[0][2], sacc[0][3]));
      float t1 = fmaxf(fmaxf(sacc[1][0], sacc[1][1]), fmaxf(sacc[1][2], sacc[1][3]));
      float t2 = fmaxf(fmaxf(sacc[2][0], sacc[2][1]), fmaxf(sacc[2][2], sacc[2][3]));
      float t3 = fmaxf(fmaxf(sacc[3][0], sacc[3][1]), fmaxf(sacc[3][2], sacc[3][3]));
      pm = fmaxf(fmaxf(t0, t1), fmaxf(t2, t3));
    }
    pm = fmaxf(pm, __shfl_xor(pm, 16, 64));
    pm = fmaxf(pm, __shfl_xor(pm, 32, 64));

    // ---- defer-max rescale (T13) ----
    if (!__all(pm <= m)) {
      const float mn = fmaxf(m, pm);
      const float sc = exp2f(m - mn);
      m = mn; l *= sc;
      #pragma unroll
      for (int j = 0; j < 4; ++j)
        #pragma unroll
        for (int r = 0; r < 4; ++r) oacc[j][r] *= sc;
    }

    // ---- P = 2^(S - m), row sum, pack to bf16 pairs ----
    float p[4][4];
    #pragma unroll
    for (int n = 0; n < 4; ++n)
      #pragma unroll
      for (int r = 0; r < 4; ++r) p[n][r] = exp2f(sacc[n][r] - m);
    float rs = ((p[0][0] + p[0][1]) + (p[0][2] + p[0][3]))
             + ((p[1][0] + p[1][1]) + (p[1][2] + p[1][3]))
             + ((p[2][0] + p[2][1]) + (p[2][2] + p[2][3]))
             + ((p[3][0] + p[3][1]) + (p[3][2] + p[3][3]));
    rs += __shfl_xor(rs, 16, 64);
    rs += __shfl_xor(rs, 32, 64);
    l += rs;

    uint32_t w32[4][2];
    #pragma unroll
    for (int n = 0; n < 4; ++n)
      #pragma unroll
      for (int c = 0; c < 2; ++c)
        asm("v_cvt_pk_bf16_f32 %0, %1, %2"
            : "=v"(w32[n][c]) : "v"(p[n][2 * c]), "v"(p[n][2 * c + 1]));

    // ---- O^T += V^T P^T ----
#if HAVE_MFMA161616
    #pragma unroll
    for (int j = 0; j < 4; ++j) {
      #pragma unroll
      for (int n = 0; n < 4; ++n) {
        union { uint32_t u[2]; short4v s; } pb;
        pb.u[0] = w32[n][0]; pb.u[1] = w32[n][1];
        oacc[j] = __builtin_amdgcn_mfma_f32_16x16x16bf16_1k(vf[j][n], pb.s,
                                                            oacc[j], 0, 0, 0);
      }
    }
#else
    // exchange p-words across lq lanes into K=32 B-frags
    union { uint32_t u[4]; bf16x8 v; } pf0, pf1;
    #pragma unroll
    for (int aa = 0; aa < 4; ++aa) {
      const int src = l16 + ((((lq << 1) + (aa >> 1)) & 3) << 4);
      uint32_t lo0 = (uint32_t)__shfl((int)w32[0][aa & 1], src, 64);
      uint32_t hi0 = (uint32_t)__shfl((int)w32[1][aa & 1], src, 64);
      uint32_t lo1 = (uint32_t)__shfl((int)w32[2][aa & 1], src, 64);
      uint32_t hi1 = (uint32_t)__shfl((int)w32[3][aa & 1], src, 64);
      pf0.u[aa] = (lq & 2) ? hi0 : lo0;
      pf1.u[aa] = (lq & 2) ? hi1 : lo1;
    }
    #pragma unroll
    for (int j = 0; j < 4; ++j) {
      oacc[j] = mfma16(vf[j][0], pf0.v, oacc[j]);
      oacc[j] = mfma16(vf[j][1], pf1.v, oacc[j]);
    }
#endif

    // rotate prefetched K
    #pragma unroll
    for (int n = 0; n < 4; ++n) {
      kc[n][0] = kn[n][0];
      kc[n][1] = kn[n][1];
    }
  }

  const float inv = 1.0f / l;
  #pragma unroll
  for (int j = 0; j < 4; ++j) {
    float4 o;
    o.x = oacc[j][0] * inv; o.y = oacc[j][1] * inv;
    o.z = oacc[j][2] * inv; o.w = oacc[j][3] * inv;
    *(float4*)&out[(bT + q0 + l16) * HDIM + j * 16 + lq * 4] = o;
  }
}

// ---------------------------------------------------------------------------
extern "C" void kernel_launch(void* const* d_in, const int* in_sizes, int n_in,
                              void* d_out, int out_size, void* d_ws, size_t ws_size,
                              hipStream_t stream) {
  (void)in_sizes; (void)n_in; (void)out_size; (void)ws_size;
  const float* x  = (const float*)d_in[0];
  const float* Wq = (const float*)d_in[1];
  const float* Wk = (const float*)d_in[2];
  const float* Wv = (const float*)d_in[3];

  const size_t qkvb = (size_t)BATCH * SEQ * HDIM * sizeof(short);  // 4 MB each
  char* ws = (char*)d_ws;
  short* qb = (short*)(ws);
  short* kb = (short*)(ws + qkvb);
  short* vT = (short*)(ws + 2 * qkvb);
  short* Wt = (short*)(ws + 3 * qkvb);

  wpack_kernel<<<dim3((192 * CDIM + 255) / 256), dim3(256), 0, stream>>>(Wq, Wk, Wv, Wt);
  qkv_kernel<<<dim3(BATCH * SEQ / 64), dim3(256), 0, stream>>>(x, Wt, qb, kb, vT);
  attn_kernel<<<dim3(512), dim3(256), 0, stream>>>(qb, kb, vT, (float*)d_out);
}